// Round 6
// baseline (304.891 us; speedup 1.0000x reference)
//
#include <hip/hip_runtime.h>
#include <hip/hip_bf16.h>
#include <stdint.h>

typedef __bf16 bf16_t;
typedef __bf16 bf16x8 __attribute__((ext_vector_type(8)));
typedef short short8 __attribute__((ext_vector_type(8)));
typedef float f32x4 __attribute__((ext_vector_type(4)));
typedef int int4v __attribute__((ext_vector_type(4)));

#define RS512  0.044194173824159216f   // 1/sqrt(512)
#define RS4608 0.014731391274719739f   // 1/sqrt(512*9)

// ---------------- K1: style vector  s[b][c] = (w[b,:] . lw[c,:])/sqrt(512) + lb[c]
__global__ void k_style(const float* __restrict__ w, const float* __restrict__ lw,
                        const float* __restrict__ lb, float* __restrict__ s) {
  int b = blockIdx.y;
  int c = blockIdx.x * 256 + threadIdx.x;
  const float4* wr = (const float4*)(w + b * 512);
  const float4* lr = (const float4*)(lw + (size_t)c * 512);
  float acc = 0.f;
#pragma unroll 4
  for (int d = 0; d < 128; ++d) {
    float4 a = wr[d], q = lr[d];
    acc += a.x * q.x + a.y * q.y + a.z * q.z + a.w * q.w;
  }
  s[b * 512 + c] = acc * RS512 + lb[c];
}

// ---------------- K2: wsq[o][i] = sum_k (cw*r)^2 ; bwf = bf16 weights in FRAGMENT layout
__global__ void k_wprep(const float* __restrict__ cw, float* __restrict__ wsq,
                        bf16_t* __restrict__ bwf) {
  int idx = blockIdx.x * 256 + threadIdx.x;  // o*512 + i
  int o = idx >> 9, i = idx & 511;
  float v[9];
  float ss = 0.f;
#pragma unroll
  for (int t = 0; t < 9; ++t) {
    float x = cw[(size_t)idx * 9 + t] * RS4608;
    v[t] = x;
    ss += x * x;
  }
  wsq[idx] = ss;
  int lane = (o & 15) | (((i >> 3) & 3) << 4);
  int base_blk = (i >> 5) * 32 + (o >> 4);  // c32*32 + fo
#pragma unroll
  for (int t = 0; t < 9; ++t) {
    size_t e = ((size_t)(t * 512 + base_blk) << 9) + lane * 8 + (i & 7);
    bwf[e] = (bf16_t)v[t];
  }
}

// ---------------- K3: sigma_inv[b][o] = rsqrt( sum_i s[b,i]^2 * wsq[o,i] + eps )
__global__ void k_sigma(const float* __restrict__ s, const float* __restrict__ wsq,
                        float* __restrict__ sinv) {
  __shared__ float s2[512];
  int b = blockIdx.y;
  int o = blockIdx.x * 256 + threadIdx.x;
  for (int i = threadIdx.x; i < 512; i += 256) {
    float v = s[b * 512 + i];
    s2[i] = v * v;
  }
  __syncthreads();
  const float4* qr = (const float4*)(wsq + (size_t)o * 512);
  float acc = 0.f;
#pragma unroll 4
  for (int d = 0; d < 128; ++d) {
    float4 q = qr[d];
    acc += q.x * s2[4 * d] + q.y * s2[4 * d + 1] + q.z * s2[4 * d + 2] + q.w * s2[4 * d + 3];
  }
  sinv[b * 512 + o] = rsqrtf(acc + 1e-8f);
}

// ---------------- K4: xt[b][h][w][ch] = bf16( x[b][ch][h][w] * s[b][ch] ), 8-ch groups
// within each 32-ch chunk XOR-permuted by ((w>>1)&3) so k_conv's ds_read is conflict-free.
__global__ void k_xt(const float* __restrict__ x, const float* __restrict__ s,
                     bf16_t* __restrict__ xt) {
  int ic = blockIdx.x, h = blockIdx.y, b = blockIdx.z;
  __shared__ __align__(16) bf16_t tile[8192];
  int t = threadIdx.x;
  int wcol = t & 63;
  int g = t >> 6;
#pragma unroll
  for (int blk = 0; blk < 4; ++blk) {
    int grp = blk * 4 + g;
    bf16x8 vec;
#pragma unroll
    for (int k = 0; k < 8; ++k) {
      int i = ic * 128 + grp * 8 + k;
      float v = x[(((size_t)b * 512 + i) * 64 + h) * 64 + wcol] * s[b * 512 + i];
      vec[k] = (bf16_t)v;
    }
    int chunk = grp ^ (wcol & 15);
    *(bf16x8*)((char*)tile + wcol * 256 + chunk * 16) = vec;
  }
  __syncthreads();
#pragma unroll
  for (int j = 0; j < 4; ++j) {
    int flat = j * 256 + t;
    int wo = flat >> 4, ig8 = flat & 15;
    int chunk = ig8 ^ (wo & 15);
    bf16x8 v = *(bf16x8*)((char*)tile + wo * 256 + chunk * 16);
    int c32 = (ig8 >> 2);
    int slot = (ig8 & 3) ^ ((wo >> 1) & 3);
    *(bf16x8*)(xt + (((size_t)b * 64 + h) * 64 + wo) * 512 + ic * 128 + c32 * 32 + slot * 8) = v;
  }
}

// ---------------- K5: implicit-GEMM conv; counted-vmcnt pipeline; DPP column-shift reuse
#define AS1 __attribute__((address_space(1)))
#define AS3 __attribute__((address_space(3)))

__device__ __forceinline__ void gl16(const void* g, void* l) {
  __builtin_amdgcn_global_load_lds((const AS1 void*)g, (AS3 void*)l, 16, 0, 0);
}

#define VMCNT(n) asm volatile("s_waitcnt vmcnt(" #n ")" ::: "memory")

// row_ror:1  (0x121): lane i <- lane (i-1)&15 within each 16-lane row
// row_ror:15 (0x12F): lane i <- lane (i+1)&15
__device__ __forceinline__ int4v dpp_ror1(int4v v) {
  int4v r;
  r[0] = __builtin_amdgcn_mov_dpp(v[0], 0x121, 0xf, 0xf, true);
  r[1] = __builtin_amdgcn_mov_dpp(v[1], 0x121, 0xf, 0xf, true);
  r[2] = __builtin_amdgcn_mov_dpp(v[2], 0x121, 0xf, 0xf, true);
  r[3] = __builtin_amdgcn_mov_dpp(v[3], 0x121, 0xf, 0xf, true);
  return r;
}
__device__ __forceinline__ int4v dpp_rol1(int4v v) {
  int4v r;
  r[0] = __builtin_amdgcn_mov_dpp(v[0], 0x12F, 0xf, 0xf, true);
  r[1] = __builtin_amdgcn_mov_dpp(v[1], 0x12F, 0xf, 0xf, true);
  r[2] = __builtin_amdgcn_mov_dpp(v[2], 0x12F, 0xf, 0xf, true);
  r[3] = __builtin_amdgcn_mov_dpp(v[3], 0x12F, 0xf, 0xf, true);
  return r;
}
__device__ __forceinline__ int4v sel4(bool c, int4v a, int4v b) {
  int4v r;
  r[0] = c ? a[0] : b[0];
  r[1] = c ? a[1] : b[1];
  r[2] = c ? a[2] : b[2];
  r[3] = c ? a[3] : b[3];
  return r;
}

// LDS map: X[2][6 rows][4096B] @0..49151 ; W[3][8192B] @49152..73727 ; scratch 4KB @73728
__global__ __launch_bounds__(256, 2) void k_conv(
    const bf16_t* __restrict__ xt, const bf16_t* __restrict__ bwf,
    const float* __restrict__ sinv, const float* __restrict__ noise,
    const float* __restrict__ snz, const float* __restrict__ bias,
    float* __restrict__ out) {
  __shared__ __align__(16) char lds[77824];

  const int t = threadIdx.x;
  const int rq = blockIdx.x;        // output rows h0..h0+3
  const int oy = blockIdx.y;        // o0 = oy*128
  const int b = blockIdx.z;
  const int h0 = rq * 4;
  const int lane = t & 63;
  const int wv = t >> 6;
  const int wm = wv >> 1;           // o-offset wm*64
  const int wn = wv & 1;            // rows h0+wn*2 .. +1

  const bf16_t* xb = xt + (size_t)b * 2097152;
  const bf16_t* wsrc = bwf + (((size_t)(oy * 8 + wv * 2)) << 9) + lane * 8;

  f32x4 acc[4][8] = {};
  int4v F[8];                       // center fragments, live across a ky-group
  const bool c0 = (lane & 15) == 0;
  const bool c15 = (lane & 15) == 15;

  auto stageXrow = [&](int c, int buf, int r) {
    int gr = h0 - 1 + r;
    if ((unsigned)gr < 64u) {
      gl16(xb + (size_t)gr * 32768 + (size_t)(t >> 2) * 512 + c * 32 + (t & 3) * 8,
           lds + buf * 24576 + r * 4096 + (wv << 10));
    } else {
      // dummy load into scratch: keeps per-wave vmem counts uniform for vmcnt(N)
      gl16(xb + (size_t)(t >> 2) * 512 + c * 32 + (t & 3) * 8, lds + 73728 + (wv << 10));
    }
  };

  auto stageW = [&](int cc, int tt, int buf) {  // 8KB: 2 gl16/thread
    const bf16_t* s0 = wsrc + (size_t)(tt * 16 + cc) * 16384;
    char* d0 = lds + 49152 + buf * 8192 + (wv << 11);
    gl16(s0, d0);
    gl16(s0 + 512, d0 + 1024);
  };

  auto compute_tap = [&](int xbuf, int tap) {
    const int ky = tap / 3, kx = tap % 3;
    const char* wbse = lds + 49152 + (tap % 3) * 8192 + (wm << 12) + (lane << 4);
    bf16x8 af[4];
#pragma unroll
    for (int mi = 0; mi < 4; ++mi) af[mi] = *(const bf16x8*)(wbse + mi * 1024);

    __builtin_amdgcn_s_setprio(1);
    if (kx == 0) {
      // load the 8 center fragments for this ky (only B-LDS-reads of the ky-group)
#pragma unroll
      for (int ni = 0; ni < 8; ++ni) {
        const int rslot = wn * 2 + (ni >> 2) + ky;
        const int icol = (ni & 3) * 16 + (lane & 15);
        const int slot = (lane >> 4) ^ ((icol >> 1) & 3);
        F[ni] = *(const int4v*)(lds + xbuf * 24576 + rslot * 4096 + icol * 64 + slot * 16);
      }
#pragma unroll
      for (int ni = 0; ni < 8; ++ni) {
        int4v g = dpp_ror1(F[ni]);                                   // lane c <- c-1
        int4v p = ((ni & 3) == 0) ? (int4v)0 : dpp_ror1(F[ni - 1]);  // group edge patch
        int4v bv = sel4(c0, p, g);
#pragma unroll
        for (int mi = 0; mi < 4; ++mi)
          acc[mi][ni] = __builtin_amdgcn_mfma_f32_16x16x32_bf16(
              af[mi], __builtin_bit_cast(bf16x8, bv), acc[mi][ni], 0, 0, 0);
      }
    } else if (kx == 1) {
#pragma unroll
      for (int ni = 0; ni < 8; ++ni) {
#pragma unroll
        for (int mi = 0; mi < 4; ++mi)
          acc[mi][ni] = __builtin_amdgcn_mfma_f32_16x16x32_bf16(
              af[mi], __builtin_bit_cast(bf16x8, F[ni]), acc[mi][ni], 0, 0, 0);
      }
    } else {
#pragma unroll
      for (int ni = 0; ni < 8; ++ni) {
        int4v g = dpp_rol1(F[ni]);                                   // lane c <- c+1
        int4v p = ((ni & 3) == 3) ? (int4v)0 : dpp_rol1(F[ni + 1]);  // group edge patch
        int4v bv = sel4(c15, p, g);
#pragma unroll
        for (int mi = 0; mi < 4; ++mi)
          acc[mi][ni] = __builtin_amdgcn_mfma_f32_16x16x32_bf16(
              af[mi], __builtin_bit_cast(bf16x8, bv), acc[mi][ni], 0, 0, 0);
      }
    }
    __builtin_amdgcn_s_setprio(0);
  };

// phase body: X-issue, W-stage(+2 taps ahead), counted vmcnt, barrier, compute.
// N = vmem issued after the stage of W[tap] in program order:
//   normal chunks: {5,6,6,6,6,6,5,4,4} ; last chunk: {4,4,4,4,4,4,4,2,0}
#define PHASE(c, tp, LAST)                                                     \
  {                                                                            \
    if (!(LAST) && (tp) < 6) stageXrow((c) + 1, (((c)&1) ^ 1), (tp));          \
    if (!(LAST) || (tp) <= 6) {                                                \
      if ((tp) + 2 <= 8) stageW((c), (tp) + 2, ((tp) + 2) % 3);                \
      else stageW((c) + 1, (tp) - 7, ((tp) + 2) % 3);                          \
    }                                                                          \
    if (LAST) {                                                                \
      if ((tp) <= 6) { VMCNT(4); }                                             \
      else if ((tp) == 7) { VMCNT(2); }                                        \
      else { VMCNT(0); }                                                       \
    } else {                                                                   \
      if ((tp) == 0 || (tp) == 6) { VMCNT(5); }                                \
      else if ((tp) <= 5) { VMCNT(6); }                                        \
      else { VMCNT(4); }                                                       \
    }                                                                          \
    __builtin_amdgcn_s_barrier();                                              \
    compute_tap((c) & 1, (tp));                                                \
  }

  // prologue: halo zeros (rows never gl16-targeted), then X[0] + W taps 0,1
  if (h0 == 0) {
    *(f32x4*)(lds + t * 16) = (f32x4)0.f;
    *(f32x4*)(lds + 24576 + t * 16) = (f32x4)0.f;
  }
  if (h0 == 60) {
    *(f32x4*)(lds + 5 * 4096 + t * 16) = (f32x4)0.f;
    *(f32x4*)(lds + 24576 + 5 * 4096 + t * 16) = (f32x4)0.f;
  }
  asm volatile("s_waitcnt lgkmcnt(0)" ::: "memory");
#pragma unroll
  for (int r = 0; r < 6; ++r) stageXrow(0, 0, r);
  stageW(0, 0, 0);
  stageW(0, 1, 1);

  for (int c = 0; c < 15; ++c) {
#pragma unroll
    for (int tp = 0; tp < 9; ++tp) PHASE(c, tp, 0);
  }
#pragma unroll
  for (int tp = 0; tp < 9; ++tp) PHASE(15, tp, 1);

  // epilogue: demod scale + noise + bias + leaky relu
  const float* sb = sinv + b * 512;
  const int og = oy * 128 + wm * 64 + ((lane >> 4) << 2);
  const int colb = lane & 15;
  float nzv[8];
#pragma unroll
  for (int ni = 0; ni < 8; ++ni) {
    int prow = h0 + wn * 2 + (ni >> 2);
    int col = (ni & 3) * 16 + colb;
    nzv[ni] = noise[(size_t)b * 4096 + prow * 64 + col];
  }
#pragma unroll
  for (int mi = 0; mi < 4; ++mi) {
#pragma unroll
    for (int r = 0; r < 4; ++r) {
      int o = og + mi * 16 + r;
      float sv = sb[o];
      float nw = snz[o];
      float bv = bias[o];
      float* obase = out + ((size_t)b * 512 + o) * 4096;
#pragma unroll
      for (int ni = 0; ni < 8; ++ni) {
        int prow = h0 + wn * 2 + (ni >> 2);
        int col = (ni & 3) * 16 + colb;
        float v = acc[mi][ni][r] * sv + nw * nzv[ni] + bv;
        obase[prow * 64 + col] = v > 0.f ? v : 0.2f * v;
      }
    }
  }
}

extern "C" void kernel_launch(void* const* d_in, const int* in_sizes, int n_in,
                              void* d_out, int out_size, void* d_ws, size_t ws_size,
                              hipStream_t stream) {
  const float* x     = (const float*)d_in[0];
  const float* w     = (const float*)d_in[1];
  const float* noise = (const float*)d_in[2];
  const float* lw    = (const float*)d_in[3];
  const float* lb    = (const float*)d_in[4];
  const float* cw    = (const float*)d_in[5];
  const float* snz   = (const float*)d_in[6];
  const float* bias  = (const float*)d_in[7];
  float* out = (float*)d_out;

  char* ws = (char*)d_ws;
  bf16_t* xt   = (bf16_t*)ws;                   // 67,108,864 B
  bf16_t* bwf  = (bf16_t*)(ws + 67108864);      //  4,718,592 B
  float*  s    = (float*)(ws + 71827456);       //     32,768 B
  float*  sinv = (float*)(ws + 71860224);       //     32,768 B
  float*  wsq  = (float*)(ws + 71892992);       //  1,048,576 B

  k_style<<<dim3(2, 16), 256, 0, stream>>>(w, lw, lb, s);
  k_wprep<<<dim3(1024), 256, 0, stream>>>(cw, wsq, bwf);
  k_sigma<<<dim3(2, 16), 256, 0, stream>>>(s, wsq, sinv);
  k_xt<<<dim3(4, 64, 16), 256, 0, stream>>>(x, s, xt);
  k_conv<<<dim3(16, 4, 16), 256, 0, stream>>>(xt, bwf, sinv, noise, snz, bias, out);
}

// Round 7
// 299.751 us; speedup vs baseline: 1.0171x; 1.0171x over previous
//
#include <hip/hip_runtime.h>
#include <hip/hip_bf16.h>
#include <stdint.h>

typedef __bf16 bf16_t;
typedef __bf16 bf16x8 __attribute__((ext_vector_type(8)));
typedef short short8 __attribute__((ext_vector_type(8)));
typedef float f32x4 __attribute__((ext_vector_type(4)));

#define RS512  0.044194173824159216f   // 1/sqrt(512)
#define RS4608 0.014731391274719739f   // 1/sqrt(512*9)

// ---------------- K1: style vector  s[b][c] = (w[b,:] . lw[c,:])/sqrt(512) + lb[c]
__global__ void k_style(const float* __restrict__ w, const float* __restrict__ lw,
                        const float* __restrict__ lb, float* __restrict__ s) {
  int b = blockIdx.y;
  int c = blockIdx.x * 256 + threadIdx.x;
  const float4* wr = (const float4*)(w + b * 512);
  const float4* lr = (const float4*)(lw + (size_t)c * 512);
  float acc = 0.f;
#pragma unroll 4
  for (int d = 0; d < 128; ++d) {
    float4 a = wr[d], q = lr[d];
    acc += a.x * q.x + a.y * q.y + a.z * q.z + a.w * q.w;
  }
  s[b * 512 + c] = acc * RS512 + lb[c];
}

// ---------------- K2: wsq[o][i] = sum_k (cw*r)^2 ; bwf = bf16 weights in FRAGMENT layout
__global__ void k_wprep(const float* __restrict__ cw, float* __restrict__ wsq,
                        bf16_t* __restrict__ bwf) {
  int idx = blockIdx.x * 256 + threadIdx.x;  // o*512 + i
  int o = idx >> 9, i = idx & 511;
  float v[9];
  float ss = 0.f;
#pragma unroll
  for (int t = 0; t < 9; ++t) {
    float x = cw[(size_t)idx * 9 + t] * RS4608;
    v[t] = x;
    ss += x * x;
  }
  wsq[idx] = ss;
  int lane = (o & 15) | (((i >> 3) & 3) << 4);
  int base_blk = (i >> 5) * 32 + (o >> 4);  // c32*32 + fo
#pragma unroll
  for (int t = 0; t < 9; ++t) {
    size_t e = ((size_t)(t * 512 + base_blk) << 9) + lane * 8 + (i & 7);
    bwf[e] = (bf16_t)v[t];
  }
}

// ---------------- K3: sigma_inv[b][o] = rsqrt( sum_i s[b,i]^2 * wsq[o,i] + eps )
__global__ void k_sigma(const float* __restrict__ s, const float* __restrict__ wsq,
                        float* __restrict__ sinv) {
  __shared__ float s2[512];
  int b = blockIdx.y;
  int o = blockIdx.x * 256 + threadIdx.x;
  for (int i = threadIdx.x; i < 512; i += 256) {
    float v = s[b * 512 + i];
    s2[i] = v * v;
  }
  __syncthreads();
  const float4* qr = (const float4*)(wsq + (size_t)o * 512);
  float acc = 0.f;
#pragma unroll 4
  for (int d = 0; d < 128; ++d) {
    float4 q = qr[d];
    acc += q.x * s2[4 * d] + q.y * s2[4 * d + 1] + q.z * s2[4 * d + 2] + q.w * s2[4 * d + 3];
  }
  sinv[b * 512 + o] = rsqrtf(acc + 1e-8f);
}

// ---------------- K4: xt[b][h][w][ch] = bf16( x[b][ch][h][w] * s[b][ch] ), 8-ch groups
// within each 32-ch chunk XOR-permuted by ((w>>1)&3) so k_conv's ds_read is conflict-free.
__global__ void k_xt(const float* __restrict__ x, const float* __restrict__ s,
                     bf16_t* __restrict__ xt) {
  int ic = blockIdx.x, h = blockIdx.y, b = blockIdx.z;
  __shared__ __align__(16) bf16_t tile[8192];
  int t = threadIdx.x;
  int wcol = t & 63;
  int g = t >> 6;
#pragma unroll
  for (int blk = 0; blk < 4; ++blk) {
    int grp = blk * 4 + g;
    bf16x8 vec;
#pragma unroll
    for (int k = 0; k < 8; ++k) {
      int i = ic * 128 + grp * 8 + k;
      float v = x[(((size_t)b * 512 + i) * 64 + h) * 64 + wcol] * s[b * 512 + i];
      vec[k] = (bf16_t)v;
    }
    int chunk = grp ^ (wcol & 15);
    *(bf16x8*)((char*)tile + wcol * 256 + chunk * 16) = vec;
  }
  __syncthreads();
#pragma unroll
  for (int j = 0; j < 4; ++j) {
    int flat = j * 256 + t;
    int wo = flat >> 4, ig8 = flat & 15;
    int chunk = ig8 ^ (wo & 15);
    bf16x8 v = *(bf16x8*)((char*)tile + wo * 256 + chunk * 16);
    int c32 = (ig8 >> 2);
    int slot = (ig8 & 3) ^ ((wo >> 1) & 3);
    *(bf16x8*)(xt + (((size_t)b * 64 + h) * 64 + wo) * 512 + ic * 128 + c32 * 32 + slot * 8) = v;
  }
}

// ---------------- K5: implicit-GEMM conv; counted-vmcnt pipeline; persistent addressing
#define AS1 __attribute__((address_space(1)))
#define AS3 __attribute__((address_space(3)))

__device__ __forceinline__ void gl16(const void* g, void* l) {
  __builtin_amdgcn_global_load_lds((const AS1 void*)g, (AS3 void*)l, 16, 0, 0);
}

#define VMCNT(n) asm volatile("s_waitcnt vmcnt(" #n ")" ::: "memory")

// LDS map: W[3][8192B] @0..24575 ; X[2][6 rows][4096B] @24576..73727 ; scratch 4KB @73728
__global__ __launch_bounds__(256, 2) void k_conv(
    const bf16_t* __restrict__ xt, const bf16_t* __restrict__ bwf,
    const float* __restrict__ sinv, const float* __restrict__ noise,
    const float* __restrict__ snz, const float* __restrict__ bias,
    float* __restrict__ out) {
  __shared__ __align__(16) char lds[77824];

  const int t = threadIdx.x;
  const int rq = blockIdx.x;        // output rows h0..h0+3
  const int oy = blockIdx.y;        // o0 = oy*128
  const int b = blockIdx.z;
  const int h0 = rq * 4;
  const int lane = t & 63;
  const int wv = t >> 6;
  const int wm = wv >> 1;           // o-offset wm*64
  const int wn = wv & 1;            // rows h0+wn*2 .. +1

  // persistent byte-based staging pointers (lane parts folded in once)
  const char* xg = (const char*)xt + (size_t)b * 4194304 + (t >> 2) * 1024 + (t & 3) * 16;
  const char* wg = (const char*)bwf + ((size_t)(oy * 8 + wv * 2) << 10) + (lane << 4);

  f32x4 acc[4][8] = {};

  // persistent LDS read offsets: A-frag base and 12 B-frag column offsets
  const uint32_t woff = (uint32_t)((wm << 12) + (lane << 4));  // W region @0
  uint32_t pXcol[4][3];
#pragma unroll
  for (int j = 0; j < 4; ++j)
#pragma unroll
    for (int dk = 0; dk < 3; ++dk) {
      int icol = j * 16 + (lane & 15) + dk - 1;
      int ic2 = icol < 0 ? 0 : (icol > 63 ? 63 : icol);
      int slot = (lane >> 4) ^ ((ic2 >> 1) & 3);
      pXcol[j][dk] = (uint32_t)(24576 + wn * 8192 + ic2 * 64 + slot * 16);
    }
  const bool c0 = (lane & 15) == 0;
  const bool c15 = (lane & 15) == 15;

  auto stageXrow = [&](int c, int buf, int r) {
    int gr = h0 - 1 + r;
    if ((unsigned)gr < 64u) {
      gl16(xg + (size_t)gr * 65536 + c * 64, lds + 24576 + buf * 24576 + r * 4096 + (wv << 10));
    } else {
      // dummy load into scratch: keeps per-wave vmem counts uniform for vmcnt(N)
      gl16(xg + c * 64, lds + 73728 + (wv << 10));
    }
  };

  auto stageW = [&](int cc, int tt, int buf) {  // 8KB: 2 gl16/thread
    const char* s0 = wg + (size_t)(tt * 16 + cc) * 32768;
    char* d0 = lds + buf * 8192 + (wv << 11);
    gl16(s0, d0);
    gl16(s0 + 1024, d0 + 1024);
  };

  // XB and tap are always compile-time constants at the call sites -> imms fold
  auto compute_tap = [&](int XB, int tap) {
    const int ky = tap / 3, kx = tap % 3;
    bf16x8 af[4];
#pragma unroll
    for (int mi = 0; mi < 4; ++mi)
      af[mi] = *(const bf16x8*)(lds + woff + (uint32_t)((tap % 3) * 8192 + mi * 1024));
    bf16x8 bfr[8];
#pragma unroll
    for (int ni = 0; ni < 8; ++ni) {
      short8 xv = *(const short8*)(lds + pXcol[ni & 3][kx] +
                                   (uint32_t)(XB * 24576 + ((ni >> 2) + ky) * 4096));
      if (kx == 0 && (ni & 3) == 0) xv = c0 ? (short8)0 : xv;    // left image edge
      if (kx == 2 && (ni & 3) == 3) xv = c15 ? (short8)0 : xv;   // right image edge
      bfr[ni] = __builtin_bit_cast(bf16x8, xv);
    }
    __builtin_amdgcn_s_setprio(1);
#pragma unroll
    for (int mi = 0; mi < 4; ++mi)
#pragma unroll
      for (int ni = 0; ni < 8; ++ni)
        acc[mi][ni] =
            __builtin_amdgcn_mfma_f32_16x16x32_bf16(af[mi], bfr[ni], acc[mi][ni], 0, 0, 0);
    __builtin_amdgcn_s_setprio(0);
  };

// phase body: X-issue, W-stage(+2 taps ahead), counted vmcnt, barrier, compute.
// N = vmem issued after the stage of W[tap] in program order:
//   normal chunks: {5,6,6,6,6,6,5,4,4} ; last chunk: {4,4,4,4,4,4,4,2,0}
#define PHASE(c, tp, LAST, XB)                                                 \
  {                                                                            \
    if (!(LAST) && (tp) < 6) stageXrow((c) + 1, (XB) ^ 1, (tp));               \
    if (!(LAST) || (tp) <= 6) {                                                \
      if ((tp) + 2 <= 8) stageW((c), (tp) + 2, ((tp) + 2) % 3);                \
      else stageW((c) + 1, (tp) - 7, ((tp) + 2) % 3);                          \
    }                                                                          \
    if (LAST) {                                                                \
      if ((tp) <= 6) { VMCNT(4); }                                             \
      else if ((tp) == 7) { VMCNT(2); }                                        \
      else { VMCNT(0); }                                                       \
    } else {                                                                   \
      if ((tp) == 0 || (tp) == 6) { VMCNT(5); }                                \
      else if ((tp) <= 5) { VMCNT(6); }                                        \
      else { VMCNT(4); }                                                       \
    }                                                                          \
    __builtin_amdgcn_s_barrier();                                              \
    compute_tap((XB), (tp));                                                   \
  }

  // prologue: halo zeros (rows never gl16-targeted), then X[0] + W taps 0,1
  if (h0 == 0) {
    *(f32x4*)(lds + 24576 + t * 16) = (f32x4)0.f;
    *(f32x4*)(lds + 49152 + t * 16) = (f32x4)0.f;
  }
  if (h0 == 60) {
    *(f32x4*)(lds + 24576 + 5 * 4096 + t * 16) = (f32x4)0.f;
    *(f32x4*)(lds + 49152 + 5 * 4096 + t * 16) = (f32x4)0.f;
  }
  asm volatile("s_waitcnt lgkmcnt(0)" ::: "memory");
#pragma unroll
  for (int r = 0; r < 6; ++r) stageXrow(0, 0, r);
  stageW(0, 0, 0);
  stageW(0, 1, 1);

  // chunk loop split even/odd so xbuf folds into the DS-read immediates
#pragma unroll 1
  for (int ci = 0; ci < 7; ++ci) {
    const int ce = ci * 2;
#pragma unroll
    for (int tp = 0; tp < 9; ++tp) PHASE(ce, tp, 0, 0);
#pragma unroll
    for (int tp = 0; tp < 9; ++tp) PHASE(ce + 1, tp, 0, 1);
  }
#pragma unroll
  for (int tp = 0; tp < 9; ++tp) PHASE(14, tp, 0, 0);
#pragma unroll
  for (int tp = 0; tp < 9; ++tp) PHASE(15, tp, 1, 1);

  // epilogue: demod scale + noise + bias + leaky relu
  const float* sb = sinv + b * 512;
  const int og = oy * 128 + wm * 64 + ((lane >> 4) << 2);
  const int colb = lane & 15;
  float nzv[8];
#pragma unroll
  for (int ni = 0; ni < 8; ++ni) {
    int prow = h0 + wn * 2 + (ni >> 2);
    int col = (ni & 3) * 16 + colb;
    nzv[ni] = noise[(size_t)b * 4096 + prow * 64 + col];
  }
#pragma unroll
  for (int mi = 0; mi < 4; ++mi) {
#pragma unroll
    for (int r = 0; r < 4; ++r) {
      int o = og + mi * 16 + r;
      float sv = sb[o];
      float nw = snz[o];
      float bv = bias[o];
      float* obase = out + ((size_t)b * 512 + o) * 4096;
#pragma unroll
      for (int ni = 0; ni < 8; ++ni) {
        int prow = h0 + wn * 2 + (ni >> 2);
        int col = (ni & 3) * 16 + colb;
        float v = acc[mi][ni][r] * sv + nw * nzv[ni] + bv;
        obase[prow * 64 + col] = v > 0.f ? v : 0.2f * v;
      }
    }
  }
}

extern "C" void kernel_launch(void* const* d_in, const int* in_sizes, int n_in,
                              void* d_out, int out_size, void* d_ws, size_t ws_size,
                              hipStream_t stream) {
  const float* x     = (const float*)d_in[0];
  const float* w     = (const float*)d_in[1];
  const float* noise = (const float*)d_in[2];
  const float* lw    = (const float*)d_in[3];
  const float* lb    = (const float*)d_in[4];
  const float* cw    = (const float*)d_in[5];
  const float* snz   = (const float*)d_in[6];
  const float* bias  = (const float*)d_in[7];
  float* out = (float*)d_out;

  char* ws = (char*)d_ws;
  bf16_t* xt   = (bf16_t*)ws;                   // 67,108,864 B
  bf16_t* bwf  = (bf16_t*)(ws + 67108864);      //  4,718,592 B
  float*  s    = (float*)(ws + 71827456);       //     32,768 B
  float*  sinv = (float*)(ws + 71860224);       //     32,768 B
  float*  wsq  = (float*)(ws + 71892992);       //  1,048,576 B

  k_style<<<dim3(2, 16), 256, 0, stream>>>(w, lw, lb, s);
  k_wprep<<<dim3(1024), 256, 0, stream>>>(cw, wsq, bwf);
  k_sigma<<<dim3(2, 16), 256, 0, stream>>>(s, wsq, sinv);
  k_xt<<<dim3(4, 64, 16), 256, 0, stream>>>(x, s, xt);
  k_conv<<<dim3(16, 4, 16), 256, 0, stream>>>(xt, bwf, sinv, noise, snz, bias, out);
}